// Round 9
// baseline (169.264 us; speedup 1.0000x reference)
//
#include <hip/hip_runtime.h>
#include <hip/hip_bf16.h>

constexpr int kN = 8192;
constexpr int kD = 128;
constexpr int BM = 32;      // rows per block in main kernel (2 MFMA row-tiles)
constexpr int BK = 64;      // j-chunk
constexpr int JSPLIT = 8;   // j-range splits (keeps grid at 2048 blocks)
constexpr int LDB = 66;     // padded LDS row stride: 132B = 1-bank shift per row

typedef __bf16 v8bf __attribute__((ext_vector_type(8)));
typedef float  v4f  __attribute__((ext_vector_type(4)));

// K_raw with 3 transcendentals (round-8 proven).
__device__ __forceinline__ float kraw_f(float4 ci, float sqi, float4 cj, float sqj) {
    float d2 = sqi + sqj - 2.0f * (ci.x * cj.x + ci.y * cj.y + ci.z * cj.z);
    d2 = fmaxf(d2, 1e-12f);
    float Dd = __builtin_amdgcn_sqrtf(d2);
    float a = 0.5f * (ci.w + cj.w);
    float t = a * (-0.5f * __builtin_amdgcn_logf(d2));                // -a*log2(D)
    t = fminf(fmaxf(t, -26.575424759098897f), 9.965784284662087f);   // log2(1e-8), log2(1000)
    float K = __builtin_amdgcn_exp2f(fmaf(Dd, -0.12022458674074695f, t));
    return fminf(K, 1000.0f);  // K >= 0 always
}

// --- kernel 1: pack coords+alpha into float4 (proven) ----------------------
__global__ void pack_k(const float* __restrict__ coords, const float* __restrict__ alpha,
                       float4* __restrict__ c4) {
    int j = blockIdx.x * 256 + threadIdx.x;
    if (j < kN) {
        c4[j] = make_float4(coords[3 * j], coords[3 * j + 1], coords[3 * j + 2], alpha[j]);
    }
}

// --- kernel 2: transpose latent [N][128] f32 -> latT [128][N] bf16 (proven) -
__global__ void transpose_k(const float* __restrict__ latent, __bf16* __restrict__ latT) {
    __shared__ float tile[32][33];
    int t = threadIdx.x;
    int tx = t & 31, ty = t >> 5;          // 32 x 8
    int j0 = blockIdx.x * 32, d0 = blockIdx.y * 32;
    #pragma unroll
    for (int i = 0; i < 32; i += 8)
        tile[ty + i][tx] = latent[(size_t)(j0 + ty + i) * kD + d0 + tx];
    __syncthreads();
    #pragma unroll
    for (int i = 0; i < 32; i += 8)
        latT[(size_t)(d0 + ty + i) * kN + j0 + tx] = (__bf16)tile[tx][ty + i];
}

// --- kernel 3: row partial sums -> atomicAdd into rsum (round-6/8 proven) --
__global__ __launch_bounds__(256) void rowsum_k(const float4* __restrict__ c4,
                                                float* __restrict__ rsum) {
    int w = threadIdx.x >> 6, lane = threadIdx.x & 63;
    int i = blockIdx.x * 4 + w;
    int jbase = blockIdx.y * (kN / JSPLIT);
    float4 ci = c4[i];
    float sqi = ci.x * ci.x + ci.y * ci.y + ci.z * ci.z;
    float s = 0.0f;
    #pragma unroll 4
    for (int it = 0; it < kN / JSPLIT / 64; ++it) {
        int j = jbase + it * 64 + lane;
        float4 cj = c4[j];
        float sqj = cj.x * cj.x + cj.y * cj.y + cj.z * cj.z;
        float k = kraw_f(ci, sqi, cj, sqj);
        if (j != i) s += k;
    }
    #pragma unroll
    for (int off = 32; off; off >>= 1) s += __shfl_xor(s, off, 64);
    if (lane == 0) atomicAdd(&rsum[i], s);
}

// --- kernel 4: fused K write + MFMA GEMM (r6 structure, BM=32) -------------
// Block: 256 threads (4 waves), 32 rows x (kN/JSPLIT=1024)-col strip, BK=64
// windows. K tile (32x64) computed cooperatively into LDS (each kraw once per
// block); wave w = dims [32w,32w+32) for BOTH 16-row tiles -> 4 accumulators.
__global__ __launch_bounds__(256, 2) void main_k(
    const float4* __restrict__ c4, const float* __restrict__ rsum,
    const __bf16* __restrict__ latT, float* __restrict__ outp, float* __restrict__ Kout) {

    __shared__ __bf16 Alds[BM][LDB];    // normalized K tile, bf16 (4.2 KB)
    __shared__ __bf16 Blds[kD][LDB];    // latent^T chunk [dim][k] (16.9 KB)
    __shared__ float4 c4row[BM];
    __shared__ float  sqrow[BM];
    __shared__ float  invrow[BM];

    const int t = threadIdx.x;
    const int i0 = blockIdx.x * BM;
    const int jstrip = blockIdx.y * (kN / JSPLIT);

    if (t < BM) {
        float4 ci = c4[i0 + t];
        c4row[t] = ci;
        sqrow[t] = ci.x * ci.x + ci.y * ci.y + ci.z * ci.z;
        invrow[t] = 1.0f / (rsum[i0 + t] + 1e-8f);
    }
    __syncthreads();

    const int lane = t & 63;
    const int wave = t >> 6;
    const int c = t & 63;               // K-tile column owned by this thread
    const int rbase = wave * 8;         // 8 K-tile rows owned by this thread

    // MFMA fragment addressing (r2/r6-proven mapping)
    const int arow = lane & 15;
    const int koff = (lane >> 4) * 8;
    const int dbase = wave * 32;

    v4f acc[2][2];
    #pragma unroll
    for (int rt = 0; rt < 2; ++rt)
        #pragma unroll
        for (int dt = 0; dt < 2; ++dt) acc[rt][dt] = (v4f){0.f, 0.f, 0.f, 0.f};

    for (int cb = 0; cb < kN / JSPLIT / BK; ++cb) {
        const int j0 = jstrip + cb * BK;

        // stage latT chunk: 128 dims x 64 k, 16B per thread-iter, coalesced
        #pragma unroll
        for (int it = 0; it < 4; ++it) {
            int idx = it * 256 + t;        // 0..1023
            int d = idx >> 3;              // 0..127
            int part = idx & 7;            // 8 x 16B per row
            uint4 v = *reinterpret_cast<const uint4*>(latT + (size_t)d * kN + j0 + part * 8);
            *reinterpret_cast<uint4*>(&Blds[d][part * 8]) = v;
        }

        // compute K tile (32 x 64): thread owns column c, rows rbase..rbase+7
        float4 cj = c4[j0 + c];
        float sqj = cj.x * cj.x + cj.y * cj.y + cj.z * cj.z;
        #pragma unroll
        for (int rr = 0; rr < 8; ++rr) {
            int r = rbase + rr;
            int gi = i0 + r, gj = j0 + c;
            float k = (gi == gj) ? 0.0f : kraw_f(c4row[r], sqrow[r], cj, sqj);
            float kn = k * invrow[r];
            Kout[(size_t)gi * kN + gj] = kn;          // coalesced 256B per row per wave
            Alds[r][c] = (__bf16)kn;
        }
        __syncthreads();

        // MFMA: A row-tiles {0,1}, B dim-tiles {0,1} for this wave's 32 dims
        #pragma unroll
        for (int kk = 0; kk < 2; ++kk) {
            v8bf a0 = *reinterpret_cast<const v8bf*>(&Alds[arow][kk * 32 + koff]);
            v8bf a1 = *reinterpret_cast<const v8bf*>(&Alds[16 + arow][kk * 32 + koff]);
            v8bf b0 = *reinterpret_cast<const v8bf*>(&Blds[dbase + (lane & 15)][kk * 32 + koff]);
            v8bf b1 = *reinterpret_cast<const v8bf*>(&Blds[dbase + 16 + (lane & 15)][kk * 32 + koff]);
            acc[0][0] = __builtin_amdgcn_mfma_f32_16x16x32_bf16(a0, b0, acc[0][0], 0, 0, 0);
            acc[0][1] = __builtin_amdgcn_mfma_f32_16x16x32_bf16(a0, b1, acc[0][1], 0, 0, 0);
            acc[1][0] = __builtin_amdgcn_mfma_f32_16x16x32_bf16(a1, b0, acc[1][0], 0, 0, 0);
            acc[1][1] = __builtin_amdgcn_mfma_f32_16x16x32_bf16(a1, b1, acc[1][1], 0, 0, 0);
        }
        __syncthreads();
    }

    // epilogue: D frag col = lane&15 (dim), row = (lane>>4)*4 + q  [m89 proven]
    const int row = (lane >> 4) * 4;
    const int col0 = wave * 32 + (lane & 15);
    #pragma unroll
    for (int rt = 0; rt < 2; ++rt)
        #pragma unroll
        for (int dt = 0; dt < 2; ++dt)
            #pragma unroll
            for (int q = 0; q < 4; ++q)
                atomicAdd(&outp[(size_t)(i0 + rt * 16 + row + q) * kD + col0 + dt * 16],
                          acc[rt][dt][q]);
}

extern "C" void kernel_launch(void* const* d_in, const int* in_sizes, int n_in,
                              void* d_out, int out_size, void* d_ws, size_t ws_size,
                              hipStream_t stream) {
    const float* latent = (const float*)d_in[0];
    const float* coords = (const float*)d_in[1];
    const float* alpha  = (const float*)d_in[2];

    float* outp = (float*)d_out;                    // [8192][128]
    float* Kout = (float*)d_out + (size_t)kN * kD;  // [8192][8192]

    // ws layout: byte-identical to the proven footprint.
    char* ws = (char*)d_ws;
    __bf16* latT = (__bf16*)ws;                                   // 2 MiB
    float4* c4   = (float4*)(ws + 2u * 1024 * 1024);              // 128 KiB
    float*  rsum = (float*)(ws + 2u * 1024 * 1024 + 128 * 1024);  // 32 KiB

    hipMemsetAsync(outp, 0, (size_t)kN * kD * sizeof(float), stream);
    hipMemsetAsync(rsum, 0, kN * sizeof(float), stream);

    pack_k<<<dim3(kN / 256), dim3(256), 0, stream>>>(coords, alpha, c4);
    transpose_k<<<dim3(kN / 32, kD / 32), dim3(256), 0, stream>>>(latent, latT);
    rowsum_k<<<dim3(kN / 4, JSPLIT), dim3(256), 0, stream>>>(c4, rsum);
    main_k<<<dim3(kN / BM, JSPLIT), dim3(256), 0, stream>>>(c4, rsum, latT, outp, Kout);
}

// Round 10
// 152.639 us; speedup vs baseline: 1.1089x; 1.1089x over previous
//
#include <hip/hip_runtime.h>
#include <hip/hip_bf16.h>

constexpr int kN = 8192;
constexpr int kD = 128;
constexpr int BM = 32;      // rows per block in main kernel (2 MFMA row-tiles)
constexpr int BK = 64;      // j-chunk
constexpr int JSPLIT = 8;   // j-range strips (grid at 2048 blocks)
constexpr int LDB = 66;     // A-tile LDS row stride: 132B (r9-proven, conflict-free)

typedef __bf16 v8bf __attribute__((ext_vector_type(8)));
typedef float  v4f  __attribute__((ext_vector_type(4)));

// async global->LDS, 16B per lane. LDS dest semantic: wave-uniform base +
// lane*16 (our dest = chunkbase + t*16 matches exactly). Global src is
// genuinely per-lane (pre-swizzled there).
__device__ __forceinline__ void gload16(const void* g, void* l) {
    __builtin_amdgcn_global_load_lds(
        (const __attribute__((address_space(1))) void*)g,
        (__attribute__((address_space(3))) void*)l, 16, 0, 0);
}

// K_raw with 3 transcendentals (round-8 proven).
__device__ __forceinline__ float kraw_f(float4 ci, float sqi, float4 cj, float sqj) {
    float d2 = sqi + sqj - 2.0f * (ci.x * cj.x + ci.y * cj.y + ci.z * cj.z);
    d2 = fmaxf(d2, 1e-12f);
    float Dd = __builtin_amdgcn_sqrtf(d2);
    float a = 0.5f * (ci.w + cj.w);
    float t = a * (-0.5f * __builtin_amdgcn_logf(d2));                // -a*log2(D)
    t = fminf(fmaxf(t, -26.575424759098897f), 9.965784284662087f);   // log2(1e-8), log2(1000)
    float K = __builtin_amdgcn_exp2f(fmaf(Dd, -0.12022458674074695f, t));
    return fminf(K, 1000.0f);  // K >= 0 always
}

// --- kernel 1: pack coords+alpha into float4 (proven) ----------------------
__global__ void pack_k(const float* __restrict__ coords, const float* __restrict__ alpha,
                       float4* __restrict__ c4) {
    int j = blockIdx.x * 256 + threadIdx.x;
    if (j < kN) {
        c4[j] = make_float4(coords[3 * j], coords[3 * j + 1], coords[3 * j + 2], alpha[j]);
    }
}

// --- kernel 2: transpose latent [N][128] f32 -> latT [128][N] bf16 (proven) -
__global__ void transpose_k(const float* __restrict__ latent, __bf16* __restrict__ latT) {
    __shared__ float tile[32][33];
    int t = threadIdx.x;
    int tx = t & 31, ty = t >> 5;          // 32 x 8
    int j0 = blockIdx.x * 32, d0 = blockIdx.y * 32;
    #pragma unroll
    for (int i = 0; i < 32; i += 8)
        tile[ty + i][tx] = latent[(size_t)(j0 + ty + i) * kD + d0 + tx];
    __syncthreads();
    #pragma unroll
    for (int i = 0; i < 32; i += 8)
        latT[(size_t)(d0 + ty + i) * kN + j0 + tx] = (__bf16)tile[tx][ty + i];
}

// --- kernel 3: row partial sums -> atomicAdd into rsum (round-6/8 proven) --
__global__ __launch_bounds__(256) void rowsum_k(const float4* __restrict__ c4,
                                                float* __restrict__ rsum) {
    int w = threadIdx.x >> 6, lane = threadIdx.x & 63;
    int i = blockIdx.x * 4 + w;
    int jbase = blockIdx.y * (kN / JSPLIT);
    float4 ci = c4[i];
    float sqi = ci.x * ci.x + ci.y * ci.y + ci.z * ci.z;
    float s = 0.0f;
    #pragma unroll 4
    for (int it = 0; it < kN / JSPLIT / 64; ++it) {
        int j = jbase + it * 64 + lane;
        float4 cj = c4[j];
        float sqj = cj.x * cj.x + cj.y * cj.y + cj.z * cj.z;
        float k = kraw_f(ci, sqi, cj, sqj);
        if (j != i) s += k;
    }
    #pragma unroll
    for (int off = 32; off; off >>= 1) s += __shfl_xor(s, off, 64);
    if (lane == 0) atomicAdd(&rsum[i], s);
}

// --- kernel 4: fused K write + MFMA GEMM (r9 skeleton, LDS-op-reduced) -----
// B staged via global_load_lds into linear [128][64] bf16 with XOR swizzle
// applied on the SOURCE address (byte ^= (dim&7)<<4) and undone on the frag
// read. K tile: thread owns a col-pair x 4 rows -> b32 A-writes, dwordx2
// Kout stores. MFMA/epilogue mappings identical to r9 (proven).
__global__ __launch_bounds__(256, 2) void main_k(
    const float4* __restrict__ c4, const float* __restrict__ rsum,
    const __bf16* __restrict__ latT, float* __restrict__ outp, float* __restrict__ Kout) {

    __shared__ __bf16 Alds[BM][LDB];    // 4.2 KB, normalized K tile
    __shared__ __bf16 Blin[kD * BK];    // 16 KB, swizzled physical layout
    __shared__ float4 c4row[BM];
    __shared__ float  sqrow[BM];
    __shared__ float  invrow[BM];

    const int t = threadIdx.x;
    const int i0 = blockIdx.x * BM;
    const int jstrip = blockIdx.y * (kN / JSPLIT);

    if (t < BM) {
        float4 ci = c4[i0 + t];
        c4row[t] = ci;
        sqrow[t] = ci.x * ci.x + ci.y * ci.y + ci.z * ci.z;
        invrow[t] = 1.0f / (rsum[i0 + t] + 1e-8f);
    }
    __syncthreads();

    const int lane = t & 63;
    const int wave = t >> 6;

    // K-tile compute mapping: col pair {2*c2, 2*c2+1}, rows rb..rb+3
    const int c2 = t & 31;
    const int rb = (t >> 5) * 4;

    // MFMA fragment addressing (r9-proven)
    const int arow = lane & 15;
    const int koff = (lane >> 4) * 8;          // elements
    const int dbase = wave * 32;
    const int bswz = ((dbase + arow) & 7) << 4; // source/read XOR (involution)

    // staging: dest byte = it*4096 + t*16 -> (row = it*32 + t/8, col-byte =
    // (t&7)*16); source col-byte pre-swizzled by ^((row&7)<<4)
    const int srow = t >> 3;
    const int scolb = ((t & 7) ^ (srow & 7)) << 4;

    v4f acc[2][2];
    #pragma unroll
    for (int rt = 0; rt < 2; ++rt)
        #pragma unroll
        for (int dt = 0; dt < 2; ++dt) acc[rt][dt] = (v4f){0.f, 0.f, 0.f, 0.f};

    for (int cb = 0; cb < kN / JSPLIT / BK; ++cb) {
        const int j0 = jstrip + cb * BK;

        // issue async B staging first (flies under the kraw compute)
        #pragma unroll
        for (int it = 0; it < 4; ++it) {
            int row = it * 32 + srow;
            const char* src = (const char*)latT + ((size_t)row * kN + j0) * 2 + scolb;
            char* dst = (char*)Blin + it * 4096 + t * 16;
            gload16(src, dst);
        }

        // K tile (32 x 64): cols {gjA, gjB}, rows rb..rb+3; kraw once per elem
        const int gjA = j0 + 2 * c2, gjB = gjA + 1;
        const float4 cjA = c4[gjA];
        const float4 cjB = c4[gjB];
        const float sqA = cjA.x * cjA.x + cjA.y * cjA.y + cjA.z * cjA.z;
        const float sqB = cjB.x * cjB.x + cjB.y * cjB.y + cjB.z * cjB.z;
        #pragma unroll
        for (int rr = 0; rr < 4; ++rr) {
            int r = rb + rr, gi = i0 + r;
            float kA = (gi == gjA) ? 0.0f : kraw_f(c4row[r], sqrow[r], cjA, sqA);
            float kB = (gi == gjB) ? 0.0f : kraw_f(c4row[r], sqrow[r], cjB, sqB);
            float knA = kA * invrow[r];
            float knB = kB * invrow[r];
            float2 st = {knA, knB};
            *reinterpret_cast<float2*>(Kout + (size_t)gi * kN + gjA) = st;  // 256B/row coalesced
            __bf16 hA = (__bf16)knA, hB = (__bf16)knB;
            unsigned pk = ((unsigned)*(unsigned short*)&hB << 16) | *(unsigned short*)&hA;
            *reinterpret_cast<unsigned*>(&Alds[r][2 * c2]) = pk;
        }
        __syncthreads();

        // MFMA: A row-tiles {0,1} x B dim-tiles {0,1}
        #pragma unroll
        for (int kk = 0; kk < 2; ++kk) {
            v8bf a0 = *reinterpret_cast<const v8bf*>(&Alds[arow][kk * 32 + koff]);
            v8bf a1 = *reinterpret_cast<const v8bf*>(&Alds[16 + arow][kk * 32 + koff]);
            const int bc = kk * 64 + koff * 2;    // logical byte col
            const char* bp0 = (const char*)Blin + (dbase + arow) * 128 + (bc ^ bswz);
            const char* bp1 = (const char*)Blin + (dbase + 16 + arow) * 128 + (bc ^ bswz);
            v8bf b0 = *reinterpret_cast<const v8bf*>(bp0);
            v8bf b1 = *reinterpret_cast<const v8bf*>(bp1);
            acc[0][0] = __builtin_amdgcn_mfma_f32_16x16x32_bf16(a0, b0, acc[0][0], 0, 0, 0);
            acc[0][1] = __builtin_amdgcn_mfma_f32_16x16x32_bf16(a0, b1, acc[0][1], 0, 0, 0);
            acc[1][0] = __builtin_amdgcn_mfma_f32_16x16x32_bf16(a1, b0, acc[1][0], 0, 0, 0);
            acc[1][1] = __builtin_amdgcn_mfma_f32_16x16x32_bf16(a1, b1, acc[1][1], 0, 0, 0);
        }
        __syncthreads();
    }

    // epilogue: D frag col = lane&15 (dim), row = (lane>>4)*4 + q  [m89 proven]
    const int row = (lane >> 4) * 4;
    const int col0 = wave * 32 + (lane & 15);
    #pragma unroll
    for (int rt = 0; rt < 2; ++rt)
        #pragma unroll
        for (int dt = 0; dt < 2; ++dt)
            #pragma unroll
            for (int q = 0; q < 4; ++q)
                atomicAdd(&outp[(size_t)(i0 + rt * 16 + row + q) * kD + col0 + dt * 16],
                          acc[rt][dt][q]);
}

extern "C" void kernel_launch(void* const* d_in, const int* in_sizes, int n_in,
                              void* d_out, int out_size, void* d_ws, size_t ws_size,
                              hipStream_t stream) {
    const float* latent = (const float*)d_in[0];
    const float* coords = (const float*)d_in[1];
    const float* alpha  = (const float*)d_in[2];

    float* outp = (float*)d_out;                    // [8192][128]
    float* Kout = (float*)d_out + (size_t)kN * kD;  // [8192][8192]

    // ws layout: byte-identical to the proven footprint.
    char* ws = (char*)d_ws;
    __bf16* latT = (__bf16*)ws;                                   // 2 MiB
    float4* c4   = (float4*)(ws + 2u * 1024 * 1024);              // 128 KiB
    float*  rsum = (float*)(ws + 2u * 1024 * 1024 + 128 * 1024);  // 32 KiB

    hipMemsetAsync(outp, 0, (size_t)kN * kD * sizeof(float), stream);
    hipMemsetAsync(rsum, 0, kN * sizeof(float), stream);

    pack_k<<<dim3(kN / 256), dim3(256), 0, stream>>>(coords, alpha, c4);
    transpose_k<<<dim3(kN / 32, kD / 32), dim3(256), 0, stream>>>(latent, latT);
    rowsum_k<<<dim3(kN / 4, JSPLIT), dim3(256), 0, stream>>>(c4, rsum);
    main_k<<<dim3(kN / BM, JSPLIT), dim3(256), 0, stream>>>(c4, rsum, latT, outp, Kout);
}

// Round 11
// 123.817 us; speedup vs baseline: 1.3671x; 1.2328x over previous
//
#include <hip/hip_runtime.h>
#include <hip/hip_bf16.h>

constexpr int kN = 8192;
constexpr int kD = 128;
constexpr int BM = 32;      // rows per block in main kernel (2 MFMA row-tiles)
constexpr int BK = 64;      // j-chunk
constexpr int JSPLIT = 8;   // j-range strips (grid at 2048 blocks)
constexpr int LDB = 66;     // A-tile LDS row stride: 132B (r9-proven, conflict-free)
constexpr int TB = 64;      // rowsum tile
constexpr int NB = kN / TB; // 128

typedef __bf16 v8bf __attribute__((ext_vector_type(8)));
typedef float  v4f  __attribute__((ext_vector_type(4)));

// async global->LDS, 16B per lane (r10-proven).
__device__ __forceinline__ void gload16(const void* g, void* l) {
    __builtin_amdgcn_global_load_lds(
        (const __attribute__((address_space(1))) void*)g,
        (__attribute__((address_space(3))) void*)l, 16, 0, 0);
}

// K_raw with 3 transcendentals (round-8 proven).
__device__ __forceinline__ float kraw_f(float4 ci, float sqi, float4 cj, float sqj) {
    float d2 = sqi + sqj - 2.0f * (ci.x * cj.x + ci.y * cj.y + ci.z * cj.z);
    d2 = fmaxf(d2, 1e-12f);
    float Dd = __builtin_amdgcn_sqrtf(d2);
    float a = 0.5f * (ci.w + cj.w);
    float t = a * (-0.5f * __builtin_amdgcn_logf(d2));                // -a*log2(D)
    t = fminf(fmaxf(t, -26.575424759098897f), 9.965784284662087f);   // log2(1e-8), log2(1000)
    float K = __builtin_amdgcn_exp2f(fmaf(Dd, -0.12022458674074695f, t));
    return fminf(K, 1000.0f);  // K >= 0 always
}

// --- kernel 1: pack coords+alpha into float4 (proven) ----------------------
__global__ void pack_k(const float* __restrict__ coords, const float* __restrict__ alpha,
                       float4* __restrict__ c4) {
    int j = blockIdx.x * 256 + threadIdx.x;
    if (j < kN) {
        c4[j] = make_float4(coords[3 * j], coords[3 * j + 1], coords[3 * j + 2], alpha[j]);
    }
}

// --- kernel 2: transpose latent [N][128] f32 -> latT [128][N] bf16 (proven) -
__global__ void transpose_k(const float* __restrict__ latent, __bf16* __restrict__ latT) {
    __shared__ float tile[32][33];
    int t = threadIdx.x;
    int tx = t & 31, ty = t >> 5;          // 32 x 8
    int j0 = blockIdx.x * 32, d0 = blockIdx.y * 32;
    #pragma unroll
    for (int i = 0; i < 32; i += 8)
        tile[ty + i][tx] = latent[(size_t)(j0 + ty + i) * kD + d0 + tx];
    __syncthreads();
    #pragma unroll
    for (int i = 0; i < 32; i += 8)
        latT[(size_t)(d0 + ty + i) * kN + j0 + tx] = (__bf16)tile[tx][ty + i];
}

// --- kernel 3: SYMMETRIC row sums — each kraw computed once per (i,j) pair --
// Triangular grid over 64x64 tiles (bi <= bj). Thread (w,l): column l, rows
// w*16..w*16+16. Column partial is lane-local; row sums go through an LDS
// transpose buffer (2 extra ops/kraw). Off-diag tiles credit both rsum[i]
// (row sums) and rsum[j] (col sums, = transpose row sums by symmetry); diag
// tiles credit rows only and zero j==i.
__global__ __launch_bounds__(256) void rowsum_sym_k(const float4* __restrict__ c4,
                                                    float* __restrict__ rsum) {
    __shared__ float4 rc4[TB];
    __shared__ float  rsq[TB];
    __shared__ float  rowbuf[TB][TB + 1];   // 16.25 KB

    // decode triangular pair (bi <= bj) from linear block index
    int L = blockIdx.x;
    int bi = (int)((2 * NB + 1 - sqrtf((float)((2 * NB + 1) * (2 * NB + 1) - 8 * L))) * 0.5f);
    #pragma unroll
    for (int f = 0; f < 2; ++f) {
        int s0 = bi * NB - bi * (bi - 1) / 2;
        int s1 = (bi + 1) * NB - (bi + 1) * bi / 2;
        if (L >= s1) ++bi;
        else if (L < s0) --bi;
    }
    int sbi = bi * NB - bi * (bi - 1) / 2;
    int bj = bi + (L - sbi);
    bool diag = (bi == bj);

    const int t = threadIdx.x;
    const int l = t & 63;
    const int w = t >> 6;

    if (t < TB) {
        float4 ci = c4[bi * TB + t];
        rc4[t] = ci;
        rsq[t] = ci.x * ci.x + ci.y * ci.y + ci.z * ci.z;
    }
    __syncthreads();

    float4 cj = c4[bj * TB + l];
    float sqj = cj.x * cj.x + cj.y * cj.y + cj.z * cj.z;

    float colacc = 0.f;
    #pragma unroll
    for (int rr = 0; rr < 16; ++rr) {
        int r = w * 16 + rr;
        float k = kraw_f(rc4[r], rsq[r], cj, sqj);
        if (diag && r == l) k = 0.f;
        colacc += k;
        rowbuf[r][l] = k;
    }
    __syncthreads();

    // row sums: thread t -> row r = t>>2, quarter q = t&3 (adjacent lanes)
    {
        int r = t >> 2, q = t & 3;
        float p = 0.f;
        #pragma unroll
        for (int m = 0; m < 16; ++m) p += rowbuf[r][q * 16 + m];
        p += __shfl_xor(p, 1, 64);
        p += __shfl_xor(p, 2, 64);
        if (q == 0) atomicAdd(&rsum[bi * TB + r], p);
    }
    if (!diag) atomicAdd(&rsum[bj * TB + l], colacc);
}

// --- kernel 4: fused K write + MFMA GEMM (r10 exact + row-const reg hoist) -
__global__ __launch_bounds__(256, 2) void main_k(
    const float4* __restrict__ c4, const float* __restrict__ rsum,
    const __bf16* __restrict__ latT, float* __restrict__ outp, float* __restrict__ Kout) {

    __shared__ __bf16 Alds[BM][LDB];    // 4.2 KB, normalized K tile
    __shared__ __bf16 Blin[kD * BK];    // 16 KB, swizzled physical layout
    __shared__ float4 c4row[BM];
    __shared__ float  sqrow[BM];
    __shared__ float  invrow[BM];

    const int t = threadIdx.x;
    const int i0 = blockIdx.x * BM;
    const int jstrip = blockIdx.y * (kN / JSPLIT);

    if (t < BM) {
        float4 ci = c4[i0 + t];
        c4row[t] = ci;
        sqrow[t] = ci.x * ci.x + ci.y * ci.y + ci.z * ci.z;
        invrow[t] = 1.0f / (rsum[i0 + t] + 1e-8f);
    }
    __syncthreads();

    const int lane = t & 63;
    const int wave = t >> 6;

    // K-tile compute mapping: col pair {2*c2, 2*c2+1}, rows rb..rb+3
    const int c2 = t & 31;
    const int rb = (t >> 5) * 4;

    // hoist this thread's 4 fixed rows into registers (was LDS reads per iter)
    float4 rc[4]; float rs[4], rv[4];
    #pragma unroll
    for (int rr = 0; rr < 4; ++rr) {
        rc[rr] = c4row[rb + rr];
        rs[rr] = sqrow[rb + rr];
        rv[rr] = invrow[rb + rr];
    }

    // MFMA fragment addressing (r9/r10-proven)
    const int arow = lane & 15;
    const int koff = (lane >> 4) * 8;          // elements
    const int dbase = wave * 32;
    const int bswz = ((dbase + arow) & 7) << 4; // source/read XOR (involution)

    // staging: dest byte = it*4096 + t*16 -> (row = it*32 + t/8, col-byte =
    // (t&7)*16); source col-byte pre-swizzled by ^((row&7)<<4)
    const int srow = t >> 3;
    const int scolb = ((t & 7) ^ (srow & 7)) << 4;

    v4f acc[2][2];
    #pragma unroll
    for (int rt = 0; rt < 2; ++rt)
        #pragma unroll
        for (int dt = 0; dt < 2; ++dt) acc[rt][dt] = (v4f){0.f, 0.f, 0.f, 0.f};

    for (int cb = 0; cb < kN / JSPLIT / BK; ++cb) {
        const int j0 = jstrip + cb * BK;

        // issue async B staging first (flies under the kraw compute)
        #pragma unroll
        for (int it = 0; it < 4; ++it) {
            int row = it * 32 + srow;
            const char* src = (const char*)latT + ((size_t)row * kN + j0) * 2 + scolb;
            char* dst = (char*)Blin + it * 4096 + t * 16;
            gload16(src, dst);
        }

        // K tile (32 x 64): cols {gjA, gjB}, rows rb..rb+3; kraw once per elem
        const int gjA = j0 + 2 * c2, gjB = gjA + 1;
        const float4 cjA = c4[gjA];
        const float4 cjB = c4[gjB];
        const float sqA = cjA.x * cjA.x + cjA.y * cjA.y + cjA.z * cjA.z;
        const float sqB = cjB.x * cjB.x + cjB.y * cjB.y + cjB.z * cjB.z;
        #pragma unroll
        for (int rr = 0; rr < 4; ++rr) {
            int r = rb + rr, gi = i0 + r;
            float kA = (gi == gjA) ? 0.0f : kraw_f(rc[rr], rs[rr], cjA, sqA);
            float kB = (gi == gjB) ? 0.0f : kraw_f(rc[rr], rs[rr], cjB, sqB);
            float knA = kA * rv[rr];
            float knB = kB * rv[rr];
            float2 st = {knA, knB};
            *reinterpret_cast<float2*>(Kout + (size_t)gi * kN + gjA) = st;  // 256B/row coalesced
            __bf16 hA = (__bf16)knA, hB = (__bf16)knB;
            unsigned pk = ((unsigned)*(unsigned short*)&hB << 16) | *(unsigned short*)&hA;
            *reinterpret_cast<unsigned*>(&Alds[r][2 * c2]) = pk;
        }
        __syncthreads();

        // MFMA: A row-tiles {0,1} x B dim-tiles {0,1}
        #pragma unroll
        for (int kk = 0; kk < 2; ++kk) {
            v8bf a0 = *reinterpret_cast<const v8bf*>(&Alds[arow][kk * 32 + koff]);
            v8bf a1 = *reinterpret_cast<const v8bf*>(&Alds[16 + arow][kk * 32 + koff]);
            const int bc = kk * 64 + koff * 2;    // logical byte col
            const char* bp0 = (const char*)Blin + (dbase + arow) * 128 + (bc ^ bswz);
            const char* bp1 = (const char*)Blin + (dbase + 16 + arow) * 128 + (bc ^ bswz);
            v8bf b0 = *reinterpret_cast<const v8bf*>(bp0);
            v8bf b1 = *reinterpret_cast<const v8bf*>(bp1);
            acc[0][0] = __builtin_amdgcn_mfma_f32_16x16x32_bf16(a0, b0, acc[0][0], 0, 0, 0);
            acc[0][1] = __builtin_amdgcn_mfma_f32_16x16x32_bf16(a0, b1, acc[0][1], 0, 0, 0);
            acc[1][0] = __builtin_amdgcn_mfma_f32_16x16x32_bf16(a1, b0, acc[1][0], 0, 0, 0);
            acc[1][1] = __builtin_amdgcn_mfma_f32_16x16x32_bf16(a1, b1, acc[1][1], 0, 0, 0);
        }
        __syncthreads();
    }

    // epilogue: D frag col = lane&15 (dim), row = (lane>>4)*4 + q  [m89 proven]
    const int row = (lane >> 4) * 4;
    const int col0 = wave * 32 + (lane & 15);
    #pragma unroll
    for (int rt = 0; rt < 2; ++rt)
        #pragma unroll
        for (int dt = 0; dt < 2; ++dt)
            #pragma unroll
            for (int q = 0; q < 4; ++q)
                atomicAdd(&outp[(size_t)(i0 + rt * 16 + row + q) * kD + col0 + dt * 16],
                          acc[rt][dt][q]);
}

extern "C" void kernel_launch(void* const* d_in, const int* in_sizes, int n_in,
                              void* d_out, int out_size, void* d_ws, size_t ws_size,
                              hipStream_t stream) {
    const float* latent = (const float*)d_in[0];
    const float* coords = (const float*)d_in[1];
    const float* alpha  = (const float*)d_in[2];

    float* outp = (float*)d_out;                    // [8192][128]
    float* Kout = (float*)d_out + (size_t)kN * kD;  // [8192][8192]

    // ws layout: byte-identical to the proven footprint.
    char* ws = (char*)d_ws;
    __bf16* latT = (__bf16*)ws;                                   // 2 MiB
    float4* c4   = (float4*)(ws + 2u * 1024 * 1024);              // 128 KiB
    float*  rsum = (float*)(ws + 2u * 1024 * 1024 + 128 * 1024);  // 32 KiB

    hipMemsetAsync(outp, 0, (size_t)kN * kD * sizeof(float), stream);
    hipMemsetAsync(rsum, 0, kN * sizeof(float), stream);

    pack_k<<<dim3(kN / 256), dim3(256), 0, stream>>>(coords, alpha, c4);
    transpose_k<<<dim3(kN / 32, kD / 32), dim3(256), 0, stream>>>(latent, latT);
    rowsum_sym_k<<<dim3(NB * (NB + 1) / 2), dim3(256), 0, stream>>>(c4, rsum);
    main_k<<<dim3(kN / BM, JSPLIT), dim3(256), 0, stream>>>(c4, rsum, latT, outp, Kout);
}